// Round 5
// baseline (382.368 us; speedup 1.0000x reference)
//
#include <hip/hip_runtime.h>
#include <hip/hip_bf16.h>
#include <cstdint>

typedef __bf16 bf16;
typedef __bf16 bf16x8 __attribute__((ext_vector_type(8)));
typedef float f32x4 __attribute__((ext_vector_type(4)));
typedef unsigned int u32;

#define E_TOT   262144
#define NNODE   512
#define NDIM    128
#define EDIM    64
#define GDIM    32
#define FIN     320
#define XD      352   // FIN + CTX(32)
#define H1D     256
#define OUTD    64
#define AHD     64
#define NHEADS  4
#define NSEG    4096
#define TE      48    // edges per block (4 blocks/CU)

#define SX_STR  360   // 720B = 180 words, %32=20 -> 2-way alias (free)
#define SH_STR  264   // 528B = 132 words, %32=4  -> 2-way
#define SA_STR  72    // 144B = 36 words,  %32=4  -> 2-way

// fp32 params block layout (floats)
#define PRM_LNG 0
#define PRM_LNB 320
#define PRM_B1  640
#define PRM_B2  896
#define PRM_A2  960
#define PRM_AB1 1216
#define PRM_AB2 1280
#define PRM_TOT 1284

// LDS layout (bytes). sX 48x360x2=34560; sH (48x264x2=25344) overlays sX head;
// sA (48x72x2=6912) overlays sX at 25600 (ends 32512, inside 34560).
#define SMEM_SX    0
#define SMEM_SA    25600
#define SMEM_A2    34560   // float[256]  = 1024
#define SMEM_LNG   35584   // float[320]  = 1280
#define SMEM_LNB   36864   // float[320]  = 1280
#define SMEM_IDX   38144   // 3 x int[48] = 576
#define SMEM_TOT   38720   // x4 = 154880 <= 160K -> 4 blocks/CU

#define HOFF 510           // k_prep blocks >= HOFF do the segment histogram

__device__ __forceinline__ float siluf(float v) {
    return v / (1.0f + __expf(-v));
}

__device__ __forceinline__ float ldf(const void* p, size_t i, bool isb) {
    return isb ? (float)((const bf16*)p)[i] : ((const float*)p)[i];
}

// Per-wave dtype probe: 1=bf16 data, 0=fp32 data. Reads first 256 u16 of nodes.
__device__ __forceinline__ bool probe_bf16(const void* nodes, int t) {
    const unsigned short* u16 = (const unsigned short*)nodes;
    int lane = t & 63;
    int pl = 0;
    #pragma unroll
    for (int i = 0; i < 4; i++) {
        unsigned short u = u16[lane * 4 + i];
        int expo = (u >> 7) & 0xFF;
        pl += (((u & 0x7FFF) == 0) || (expo >= 97 && expo <= 137)) ? 1 : 0;
    }
    #pragma unroll
    for (int m = 1; m < 64; m <<= 1) pl += __shfl_xor(pl, m);
    return pl >= 240;
}

// ---------------- K_prep: weights transpose + params + segment histogram ----------------
__global__ __launch_bounds__(256) void k_prep(
    const void* __restrict__ nodes,
    const void* __restrict__ W1, const void* __restrict__ W2, const void* __restrict__ A1,
    const void* __restrict__ ln_g, const void* __restrict__ ln_b,
    const void* __restrict__ b1, const void* __restrict__ b2,
    const void* __restrict__ A2, const void* __restrict__ ab1, const void* __restrict__ ab2,
    const int* __restrict__ bidx, const int* __restrict__ ridx,
    bf16* __restrict__ W1T, bf16* __restrict__ W2T, bf16* __restrict__ A1T,
    float* __restrict__ prm, u32* __restrict__ hist) {
    int b = blockIdx.x, t = threadIdx.x;
    if (b >= HOFF) {                                // segment histogram (hist pre-zeroed)
        int ge = (b - HOFF) * 256 + t;
        int seg = bidx[ge] * NNODE + ridx[ge];
        atomicAdd(&hist[seg], 1u);
        return;
    }
    bool isb = probe_bf16(nodes, t);
    if (b < 352) {                                  // W1 [352][256] -> W1T [256][352]
        int i = b * 256 + t;
        int k = i / H1D, n = i % H1D;
        float v = isb ? (float)((const bf16*)W1)[i] : ((const float*)W1)[i];
        W1T[n * XD + k] = (bf16)v;
    } else if (b < 416) {                           // W2 [256][64] -> W2T [64][256]
        int i = (b - 352) * 256 + t;
        int k = i / OUTD, n = i % OUTD;
        float v = isb ? (float)((const bf16*)W2)[i] : ((const float*)W2)[i];
        W2T[n * H1D + k] = (bf16)v;
    } else if (b < 504) {                           // A1 [352][64] -> A1T [64][352]
        int i = (b - 416) * 256 + t;
        int k = i / AHD, n = i % AHD;
        float v = isb ? (float)((const bf16*)A1)[i] : ((const float*)A1)[i];
        A1T[n * XD + k] = (bf16)v;
    } else {                                        // params -> fp32 block
        int i = (b - 504) * 256 + t;
        if (i < PRM_TOT) {
            const void* src; int off;
            if (i < 320)       { src = ln_g; off = i; }
            else if (i < 640)  { src = ln_b; off = i - 320; }
            else if (i < 896)  { src = b1;   off = i - 640; }
            else if (i < 960)  { src = b2;   off = i - 896; }
            else if (i < 1216) { src = A2;   off = i - 960; }
            else if (i < 1280) { src = ab1;  off = i - 1216; }
            else               { src = ab2;  off = i - 1280; }
            prm[i] = isb ? (float)((const bf16*)src)[off] : ((const float*)src)[off];
        }
    }
}

// ---------------- K_prefix: exclusive prefix over 4096 bins (1 block) ----------------
__global__ __launch_bounds__(256) void k_prefix(const u32* __restrict__ hist,
                                                u32* __restrict__ offs,
                                                u32* __restrict__ cursor) {
    __shared__ u32 tot[256];
    __shared__ u32 base[256];
    int t = threadIdx.x;
    u32 h[16], s = 0;
    #pragma unroll
    for (int j = 0; j < 16; j++) { h[j] = hist[t * 16 + j]; s += h[j]; }
    tot[t] = s;
    __syncthreads();
    if (t == 0) {
        u32 r = 0;
        for (int i = 0; i < 256; i++) { base[i] = r; r += tot[i]; }
    }
    __syncthreads();
    u32 r = base[t];
    #pragma unroll
    for (int j = 0; j < 16; j++) {
        offs[t * 16 + j] = r;
        cursor[t * 16 + j] = r;
        r += h[j];
    }
    if (t == 255) offs[NSEG] = E_TOT;
}

// ---------------- K_scatter: order[] = edge ids bucketed by segment ----------------
__global__ __launch_bounds__(256) void k_scatter(const int* __restrict__ bidx,
                                                 const int* __restrict__ ridx,
                                                 u32* __restrict__ cursor,
                                                 u32* __restrict__ order) {
    int ge = blockIdx.x * 256 + threadIdx.x;
    int seg = bidx[ge] * NNODE + ridx[ge];
    u32 pos = atomicAdd(&cursor[seg], 1u);
    order[pos] = (u32)ge;
}

// ---------------- K1: fused per-edge-tile kernel (R0 structure, atomics removed) ----------------
__global__ __launch_bounds__(256, 4) void k_edge(
    const void* __restrict__ nodes, const void* __restrict__ edges0,
    const void* __restrict__ globs, const float* __restrict__ prm,
    const int* __restrict__ bidx, const int* __restrict__ sidx,
    const int* __restrict__ ridx,
    const bf16* __restrict__ W1T, const bf16* __restrict__ W2T,
    const bf16* __restrict__ A1T,
    void* __restrict__ outNE, float* __restrict__ scrS) {

    __shared__ __align__(16) char smem[SMEM_TOT];
    bf16*  sX    = (bf16*)(smem + SMEM_SX);
    bf16*  sH    = (bf16*)(smem + SMEM_SX);     // overlay after GEMM1 barrier
    bf16*  sA    = (bf16*)(smem + SMEM_SA);     // overlay of sX mid-region
    float* sA2   = (float*)(smem + SMEM_A2);
    float* sLnG  = (float*)(smem + SMEM_LNG);
    float* sLnB  = (float*)(smem + SMEM_LNB);
    int*   sBi   = (int*)(smem + SMEM_IDX);
    int*   sSi   = sBi + TE;
    int*   sRi   = sBi + 2 * TE;

    const int t  = threadIdx.x;
    const int e0 = blockIdx.x * TE;
    const int ne = min(TE, E_TOT - e0);          // tail block: 16
    const bool isb = probe_bf16(nodes, t);

    // Phase 0: stage indices + LN params + A2 weights (R0-proven staging)
    if (t < TE) {
        int ge = e0 + t;
        if (t < ne) {
            sBi[t] = bidx[ge]; sSi[t] = sidx[ge]; sRi[t] = ridx[ge];
        } else {
            sBi[t] = 0; sSi[t] = 0; sRi[t] = 0;
        }
    } else if (t < 128) {
        int c = t - 48;
        if (c < 80) ((float4*)sLnG)[c] = ((const float4*)(prm + PRM_LNG))[c];
    } else if (t < 208) {
        int c = t - 128;
        ((float4*)sLnB)[c] = ((const float4*)(prm + PRM_LNB))[c];
    } else {
        int c = t - 208;
        if (c < 32) {
            ((float4*)sA2)[c]      = ((const float4*)(prm + PRM_A2))[c];
            ((float4*)sA2)[c + 32] = ((const float4*)(prm + PRM_A2))[c + 32];
        }
    }
    __syncthreads();

    // Phase 1: merged gather + LayerNorm in registers (8 threads per edge)
    {
        const int eh = t >> 3, gl = t & 7;
        for (int half = 0; half < 2; half++) {
            const int e = half * 32 + eh;
            if (e >= TE) break;
            if (e >= ne) {               // tail: zero-fill so GEMMs stay finite
                bf16x8 zz = {};
                #pragma unroll
                for (int j = 0; j < 6; j++) {
                    int c = gl + j * 8;
                    if (c < 44) *(bf16x8*)&sX[e * SX_STR + c * 8] = zz;
                }
                continue;
            }
            const int ge = e0 + e;
            const int bi = sBi[e], si = sSi[e], ri = sRi[e];
            float v[40];
            #pragma unroll
            for (int j = 0; j < 5; j++) {
                const int c = gl + j * 8;
                const void* base; size_t off;
                if (c < 8)       { base = edges0; off = (size_t)ge * EDIM + c * 8; }
                else if (c < 24) { base = nodes;  off = (size_t)(bi * NNODE + si) * NDIM + (c - 8) * 8; }
                else             { base = nodes;  off = (size_t)(bi * NNODE + ri) * NDIM + (c - 24) * 8; }
                if (isb) {
                    bf16x8 x = *(const bf16x8*)((const bf16*)base + off);
                    #pragma unroll
                    for (int ii = 0; ii < 8; ii++) v[j * 8 + ii] = (float)x[ii];
                } else {
                    const float* sf = (const float*)base + off;
                    float4 f0 = ((const float4*)sf)[0];
                    float4 f1 = ((const float4*)sf)[1];
                    v[j*8+0]=f0.x; v[j*8+1]=f0.y; v[j*8+2]=f0.z; v[j*8+3]=f0.w;
                    v[j*8+4]=f1.x; v[j*8+5]=f1.y; v[j*8+6]=f1.z; v[j*8+7]=f1.w;
                }
            }
            float s = 0.f, sq = 0.f;
            #pragma unroll
            for (int ii = 0; ii < 40; ii++) { s += v[ii]; sq += v[ii] * v[ii]; }
            #pragma unroll
            for (int m = 1; m < 8; m <<= 1) { s += __shfl_xor(s, m); sq += __shfl_xor(sq, m); }
            float mean = s * (1.0f / FIN);
            float var  = sq * (1.0f / FIN) - mean * mean;
            float rstd = rsqrtf(var + 1e-5f);
            #pragma unroll
            for (int j = 0; j < 5; j++) {
                const int c = gl + j * 8;
                const float* gP = &sLnG[c * 8];
                const float* bP = &sLnB[c * 8];
                bf16x8 o;
                #pragma unroll
                for (int ii = 0; ii < 8; ii++)
                    o[ii] = (bf16)((v[j * 8 + ii] - mean) * rstd * gP[ii] + bP[ii]);
                *(bf16x8*)&sX[e * SX_STR + c * 8] = o;
            }
            if (gl < 4) {   // globs chunk c = 40+gl (not LayerNormed)
                const int c = 40 + gl;
                size_t off = (size_t)bi * GDIM + gl * 8;
                bf16x8 o;
                if (isb) {
                    o = *(const bf16x8*)((const bf16*)globs + off);
                } else {
                    const float* sf = (const float*)globs + off;
                    float4 f0 = ((const float4*)sf)[0];
                    float4 f1 = ((const float4*)sf)[1];
                    o[0]=(bf16)f0.x; o[1]=(bf16)f0.y; o[2]=(bf16)f0.z; o[3]=(bf16)f0.w;
                    o[4]=(bf16)f1.x; o[5]=(bf16)f1.y; o[6]=(bf16)f1.z; o[7]=(bf16)f1.w;
                }
                *(bf16x8*)&sX[e * SX_STR + c * 8] = o;
            }
        }
    }
    __syncthreads();

    const int w = t >> 6, lane = t & 63, quad = lane >> 4, l15 = lane & 15;
    f32x4 z = {0.f, 0.f, 0.f, 0.f};

    // Phase 2: GEMM1 X(48x352)@W1T(->256) + X@A1T(->64), B-frags double-buffered
    f32x4 acc[3][4], accA[3];
    #pragma unroll
    for (int s2 = 0; s2 < 3; s2++) { accA[s2] = z; for (int i = 0; i < 4; i++) acc[s2][i] = z; }
    {
        const bf16* pW = W1T + (size_t)(w * 64 + l15) * XD + quad * 8;
        const bf16* pA = A1T + (size_t)(w * 16 + l15) * XD + quad * 8;
        bf16x8 bw[4], ba;
        #pragma unroll
        for (int i = 0; i < 4; i++) bw[i] = *(const bf16x8*)(pW + (size_t)i * 16 * XD);
        ba = *(const bf16x8*)pA;
        for (int kk = 0; kk < 11; kk++) {
            bf16x8 bwn[4], ban;
            if (kk < 10) {
                #pragma unroll
                for (int i = 0; i < 4; i++) bwn[i] = *(const bf16x8*)(pW + (size_t)i * 16 * XD + (kk + 1) * 32);
                ban = *(const bf16x8*)(pA + (kk + 1) * 32);
            }
            const int kc = kk * 32 + quad * 8;
            bf16x8 a[3];
            #pragma unroll
            for (int s2 = 0; s2 < 3; s2++) a[s2] = *(bf16x8*)&sX[(s2 * 16 + l15) * SX_STR + kc];
            #pragma unroll
            for (int i = 0; i < 4; i++)
                #pragma unroll
                for (int s2 = 0; s2 < 3; s2++)
                    acc[s2][i] = __builtin_amdgcn_mfma_f32_16x16x32_bf16(a[s2], bw[i], acc[s2][i], 0, 0, 0);
            #pragma unroll
            for (int s2 = 0; s2 < 3; s2++)
                accA[s2] = __builtin_amdgcn_mfma_f32_16x16x32_bf16(a[s2], ba, accA[s2], 0, 0, 0);
            if (kk < 10) {
                #pragma unroll
                for (int i = 0; i < 4; i++) bw[i] = bwn[i];
                ba = ban;
            }
        }
    }
    __syncthreads();   // all sX reads done before overlay writes

    // Phase 3: epilogue -> sH (overlay) and sA (overlay)
    #pragma unroll
    for (int i = 0; i < 4; i++) {
        const int n = w * 64 + i * 16 + l15;
        const float bb = prm[PRM_B1 + n];
        #pragma unroll
        for (int s2 = 0; s2 < 3; s2++)
            #pragma unroll
            for (int r = 0; r < 4; r++)
                sH[(s2 * 16 + quad * 4 + r) * SH_STR + n] = (bf16)siluf(acc[s2][i][r] + bb);
    }
    {
        const int n = w * 16 + l15;
        const float ba1 = prm[PRM_AB1 + n];
        #pragma unroll
        for (int s2 = 0; s2 < 3; s2++)
            #pragma unroll
            for (int r = 0; r < 4; r++)
                sA[(s2 * 16 + quad * 4 + r) * SA_STR + n] = (bf16)siluf(accA[s2][r] + ba1);
    }
    __syncthreads();

    // Phase 4: scores = exp((silu(X@A1)@A2 + ab2)/8) -> plain global stream
    // (no max-sub: |logit| << 1). No atomics, no barrier after: phase 5 is
    // independent of the scores now.
    if (t < TE * NHEADS) {
        const int e = t >> 2, h = t & 3;
        if (e < ne) {
            float dot = 0.f;
            #pragma unroll
            for (int c = 0; c < 8; c++) {
                bf16x8 vv = *(bf16x8*)&sA[e * SA_STR + c * 8];
                #pragma unroll
                for (int ii = 0; ii < 8; ii++)
                    dot += (float)vv[ii] * sA2[(c * 8 + ii) * NHEADS + h];
            }
            scrS[(size_t)(e0 + e) * NHEADS + h] = __expf((dot + prm[PRM_AB2 + h]) * 0.125f);
        }
    }

    // Phase 5: GEMM2 H@W2T + b2 + edges0 -> new_edges (no pooled atomics)
    {
        f32x4 c2[3] = {z, z, z};
        const int n = w * 16 + l15;
        const bf16* pW2 = W2T + (size_t)n * H1D + quad * 8;
        bf16x8 b2f = *(const bf16x8*)pW2;
        for (int kk = 0; kk < 8; kk++) {
            bf16x8 b2n;
            if (kk < 7) b2n = *(const bf16x8*)(pW2 + (kk + 1) * 32);
            const int kc = kk * 32 + quad * 8;
            #pragma unroll
            for (int s2 = 0; s2 < 3; s2++) {
                bf16x8 a = *(bf16x8*)&sH[(s2 * 16 + l15) * SH_STR + kc];
                c2[s2] = __builtin_amdgcn_mfma_f32_16x16x32_bf16(a, b2f, c2[s2], 0, 0, 0);
            }
            if (kk < 7) b2f = b2n;
        }
        const float bb2 = prm[PRM_B2 + n];
        #pragma unroll
        for (int s2 = 0; s2 < 3; s2++)
            #pragma unroll
            for (int r = 0; r < 4; r++) {
                const int row = s2 * 16 + quad * 4 + r;
                if (row < ne) {
                    size_t off = (size_t)(e0 + row) * EDIM + n;
                    float ev = isb ? (float)((const bf16*)edges0)[off] : ((const float*)edges0)[off];
                    float v = c2[s2][r] + bb2 + ev;
                    if (isb) ((bf16*)outNE)[off] = (bf16)v;
                    else     ((float*)outNE)[off] = v;
                }
            }
    }
}

// ---------------- K_pool: gather-based segment softmax-pool (replaces atomics + k_norm) ----
// One wave per segment: lane n accumulates sum_e newE[e][n] * score[e][n>>4] and
// the per-head denominator, then writes pooled = acc/denom.
__global__ __launch_bounds__(256) void k_pool(const u32* __restrict__ offs,
                                              const u32* __restrict__ order,
                                              const float* __restrict__ scrS,
                                              const void* __restrict__ nodes,
                                              void* __restrict__ d_out) {
    const int t = threadIdx.x;
    const bool isb = probe_bf16(nodes, t);
    const int ws = blockIdx.x * 4 + (t >> 6);    // segment id, 0..4095
    const int lane = t & 63, h = lane >> 4;
    const void* newE = d_out;                    // edges region of d_out

    const u32 o0 = offs[ws], o1 = offs[ws + 1];
    float acc = 0.f, dsum = 0.f;
    u32 i = o0;
    for (; i + 4 <= o1; i += 4) {                // 4-deep to keep loads in flight
        u32 ea = order[i], eb = order[i + 1], ec = order[i + 2], ed = order[i + 3];
        float sa = scrS[(size_t)ea * NHEADS + h];
        float sb = scrS[(size_t)eb * NHEADS + h];
        float sc = scrS[(size_t)ec * NHEADS + h];
        float sd = scrS[(size_t)ed * NHEADS + h];
        float va = ldf(newE, (size_t)ea * EDIM + lane, isb);
        float vb = ldf(newE, (size_t)eb * EDIM + lane, isb);
        float vc = ldf(newE, (size_t)ec * EDIM + lane, isb);
        float vd = ldf(newE, (size_t)ed * EDIM + lane, isb);
        acc += va * sa + vb * sb + vc * sc + vd * sd;
        dsum += sa + sb + sc + sd;
    }
    for (; i < o1; i++) {
        u32 e = order[i];
        float s = scrS[(size_t)e * NHEADS + h];
        acc += ldf(newE, (size_t)e * EDIM + lane, isb) * s;
        dsum += s;
    }
    float r = (dsum > 0.f) ? acc / dsum : 0.f;
    size_t po = (size_t)E_TOT * OUTD + (size_t)ws * OUTD + lane;
    if (isb) ((bf16*)d_out)[po] = (bf16)r;
    else     ((float*)d_out)[po] = r;
}

static char* align_up(char* p, size_t a) {
    return (char*)(((uintptr_t)p + (a - 1)) & ~(uintptr_t)(a - 1));
}

extern "C" void kernel_launch(void* const* d_in, const int* in_sizes, int n_in,
                              void* d_out, int out_size, void* d_ws, size_t ws_size,
                              hipStream_t stream) {
    const void* nodes  = d_in[0];
    const void* edges0 = d_in[1];
    const void* globs  = d_in[2];
    const void* ln_g   = d_in[3];
    const void* ln_b   = d_in[4];
    const void* W1     = d_in[5];
    const void* b1     = d_in[6];
    const void* W2     = d_in[7];
    const void* b2     = d_in[8];
    const void* A1     = d_in[9];
    const void* ab1    = d_in[10];
    const void* A2     = d_in[11];
    const void* ab2    = d_in[12];
    const int*  bidx   = (const int*)d_in[13];
    const int*  sidx   = (const int*)d_in[14];
    const int*  ridx   = (const int*)d_in[15];

    char* p = (char*)d_ws;
    float* prm    = (float*)p;  p = align_up(p + PRM_TOT * 4, 256);
    bf16*  W1T    = (bf16*)p;   p = align_up(p + XD * H1D * 2, 256);
    bf16*  W2T    = (bf16*)p;   p = align_up(p + H1D * OUTD * 2, 256);
    bf16*  A1T    = (bf16*)p;   p = align_up(p + XD * AHD * 2, 256);
    u32*   hist   = (u32*)p;    p += NSEG * 4;                 // 16 KB
    u32*   offs   = (u32*)p;    p = align_up(p + (NSEG + 1) * 4, 256);
    u32*   cursor = (u32*)p;    p += NSEG * 4;                 // 16 KB
    u32*   order  = (u32*)p;    p += (size_t)E_TOT * 4;        // 1 MB
    float* scrS   = (float*)p;  p += (size_t)E_TOT * NHEADS * 4; // 4 MB

    hipMemsetAsync(hist, 0, NSEG * 4, stream);
    k_prep<<<dim3(HOFF + E_TOT / 256), dim3(256), 0, stream>>>(
        nodes, W1, W2, A1, ln_g, ln_b, b1, b2, A2, ab1, ab2,
        bidx, ridx, W1T, W2T, A1T, prm, hist);
    k_prefix<<<dim3(1), dim3(256), 0, stream>>>(hist, offs, cursor);
    k_scatter<<<dim3(E_TOT / 256), dim3(256), 0, stream>>>(bidx, ridx, cursor, order);
    k_edge<<<dim3((E_TOT + TE - 1) / TE), dim3(256), 0, stream>>>(
        nodes, edges0, globs, prm,
        bidx, sidx, ridx, W1T, W2T, A1T, d_out, scrS);
    k_pool<<<dim3(NSEG / 4), dim3(256), 0, stream>>>(offs, order, scrS, nodes, d_out);
}

// Round 6
// 333.036 us; speedup vs baseline: 1.1481x; 1.1481x over previous
//
#include <hip/hip_runtime.h>
#include <hip/hip_bf16.h>
#include <cstdint>

typedef __bf16 bf16;
typedef __bf16 bf16x8 __attribute__((ext_vector_type(8)));
typedef float f32x4 __attribute__((ext_vector_type(4)));
typedef unsigned int u32;

#define E_TOT   262144
#define NNODE   512
#define NDIM    128
#define EDIM    64
#define GDIM    32
#define FIN     320
#define XD      352   // FIN + CTX(32)
#define H1D     256
#define OUTD    64
#define AHD     64
#define NHEADS  4
#define NSEG    4096
#define TE      48    // edges per block (4 blocks/CU)
#define CAP     192   // bucket capacity; counts ~Poisson(64), P(>=192) < 1e-50

#define SX_STR  360   // 720B = 180 words, %32=20 -> 2-way alias (free)
#define SH_STR  264   // 528B = 132 words, %32=4  -> 2-way
#define SA_STR  72    // 144B = 36 words,  %32=4  -> 2-way

// fp32 params block layout (floats)
#define PRM_LNG 0
#define PRM_LNB 320
#define PRM_B1  640
#define PRM_B2  896
#define PRM_A2  960
#define PRM_AB1 1216
#define PRM_AB2 1280
#define PRM_TOT 1284

// LDS layout (bytes). sX 48x360x2=34560; sH (48x264x2=25344) overlays sX head;
// sA (48x72x2=6912) overlays sX at 25600 (ends 32512, inside 34560).
#define SMEM_SX    0
#define SMEM_SA    25600
#define SMEM_A2    34560   // float[256]  = 1024
#define SMEM_LNG   35584   // float[320]  = 1280
#define SMEM_LNB   36864   // float[320]  = 1280
#define SMEM_IDX   38144   // 3 x int[48] = 576
#define SMEM_TOT   38720   // x4 = 154880 <= 160K -> 4 blocks/CU

#define SOFF 510           // k_prep blocks >= SOFF do the single-pass bucket scatter

__device__ __forceinline__ float siluf(float v) {
    return v / (1.0f + __expf(-v));
}

__device__ __forceinline__ float ldf(const void* p, size_t i, bool isb) {
    return isb ? (float)((const bf16*)p)[i] : ((const float*)p)[i];
}

// Per-wave dtype probe: 1=bf16 data, 0=fp32 data. Reads first 256 u16 of nodes.
__device__ __forceinline__ bool probe_bf16(const void* nodes, int t) {
    const unsigned short* u16 = (const unsigned short*)nodes;
    int lane = t & 63;
    int pl = 0;
    #pragma unroll
    for (int i = 0; i < 4; i++) {
        unsigned short u = u16[lane * 4 + i];
        int expo = (u >> 7) & 0xFF;
        pl += (((u & 0x7FFF) == 0) || (expo >= 97 && expo <= 137)) ? 1 : 0;
    }
    #pragma unroll
    for (int m = 1; m < 64; m <<= 1) pl += __shfl_xor(pl, m);
    return pl >= 240;
}

// ---------------- K_prep: weights transpose + params + single-pass bucket scatter ----------
__global__ __launch_bounds__(256) void k_prep(
    const void* __restrict__ nodes,
    const void* __restrict__ W1, const void* __restrict__ W2, const void* __restrict__ A1,
    const void* __restrict__ ln_g, const void* __restrict__ ln_b,
    const void* __restrict__ b1, const void* __restrict__ b2,
    const void* __restrict__ A2, const void* __restrict__ ab1, const void* __restrict__ ab2,
    const int* __restrict__ bidx, const int* __restrict__ ridx,
    bf16* __restrict__ W1T, bf16* __restrict__ W2T, bf16* __restrict__ A1T,
    float* __restrict__ prm, u32* __restrict__ cnt, u32* __restrict__ order) {
    int b = blockIdx.x, t = threadIdx.x;
    if (b >= SOFF) {                                // bucket scatter (cnt pre-zeroed)
        int ge = (b - SOFF) * 256 + t;
        int seg = bidx[ge] * NNODE + ridx[ge];
        u32 pos = atomicAdd(&cnt[seg], 1u);
        if (pos < CAP) order[(size_t)seg * CAP + pos] = (u32)ge;
        return;
    }
    bool isb = probe_bf16(nodes, t);
    if (b < 352) {                                  // W1 [352][256] -> W1T [256][352]
        int i = b * 256 + t;
        int k = i / H1D, n = i % H1D;
        float v = isb ? (float)((const bf16*)W1)[i] : ((const float*)W1)[i];
        W1T[n * XD + k] = (bf16)v;
    } else if (b < 416) {                           // W2 [256][64] -> W2T [64][256]
        int i = (b - 352) * 256 + t;
        int k = i / OUTD, n = i % OUTD;
        float v = isb ? (float)((const bf16*)W2)[i] : ((const float*)W2)[i];
        W2T[n * H1D + k] = (bf16)v;
    } else if (b < 504) {                           // A1 [352][64] -> A1T [64][352]
        int i = (b - 416) * 256 + t;
        int k = i / AHD, n = i % AHD;
        float v = isb ? (float)((const bf16*)A1)[i] : ((const float*)A1)[i];
        A1T[n * XD + k] = (bf16)v;
    } else {                                        // params -> fp32 block
        int i = (b - 504) * 256 + t;
        if (i < PRM_TOT) {
            const void* src; int off;
            if (i < 320)       { src = ln_g; off = i; }
            else if (i < 640)  { src = ln_b; off = i - 320; }
            else if (i < 896)  { src = b1;   off = i - 640; }
            else if (i < 960)  { src = b2;   off = i - 896; }
            else if (i < 1216) { src = A2;   off = i - 960; }
            else if (i < 1280) { src = ab1;  off = i - 1216; }
            else               { src = ab2;  off = i - 1280; }
            prm[i] = isb ? (float)((const bf16*)src)[off] : ((const float*)src)[off];
        }
    }
}

// ---------------- K1: fused per-edge-tile kernel (R5 structure; k-loops rolled) ----------------
// #pragma unroll 1 on the GEMM k-loops: probe for I$-thrash (fully-unrolled body
// is ~25-30 KB of code vs 32 KB I$; 4 blocks/CU at different phases would thrash).
__global__ __launch_bounds__(256, 4) void k_edge(
    const void* __restrict__ nodes, const void* __restrict__ edges0,
    const void* __restrict__ globs, const float* __restrict__ prm,
    const int* __restrict__ bidx, const int* __restrict__ sidx,
    const int* __restrict__ ridx,
    const bf16* __restrict__ W1T, const bf16* __restrict__ W2T,
    const bf16* __restrict__ A1T,
    void* __restrict__ outNE, float* __restrict__ scrS) {

    __shared__ __align__(16) char smem[SMEM_TOT];
    bf16*  sX    = (bf16*)(smem + SMEM_SX);
    bf16*  sH    = (bf16*)(smem + SMEM_SX);     // overlay after GEMM1 barrier
    bf16*  sA    = (bf16*)(smem + SMEM_SA);     // overlay of sX mid-region
    float* sA2   = (float*)(smem + SMEM_A2);
    float* sLnG  = (float*)(smem + SMEM_LNG);
    float* sLnB  = (float*)(smem + SMEM_LNB);
    int*   sBi   = (int*)(smem + SMEM_IDX);
    int*   sSi   = sBi + TE;
    int*   sRi   = sBi + 2 * TE;

    const int t  = threadIdx.x;
    const int e0 = blockIdx.x * TE;
    const int ne = min(TE, E_TOT - e0);          // tail block: 16
    const bool isb = probe_bf16(nodes, t);

    // Phase 0: stage indices + LN params + A2 weights
    if (t < TE) {
        int ge = e0 + t;
        if (t < ne) {
            sBi[t] = bidx[ge]; sSi[t] = sidx[ge]; sRi[t] = ridx[ge];
        } else {
            sBi[t] = 0; sSi[t] = 0; sRi[t] = 0;
        }
    } else if (t < 128) {
        int c = t - 48;
        if (c < 80) ((float4*)sLnG)[c] = ((const float4*)(prm + PRM_LNG))[c];
    } else if (t < 208) {
        int c = t - 128;
        ((float4*)sLnB)[c] = ((const float4*)(prm + PRM_LNB))[c];
    } else {
        int c = t - 208;
        if (c < 32) {
            ((float4*)sA2)[c]      = ((const float4*)(prm + PRM_A2))[c];
            ((float4*)sA2)[c + 32] = ((const float4*)(prm + PRM_A2))[c + 32];
        }
    }
    __syncthreads();

    // Phase 1: merged gather + LayerNorm in registers (8 threads per edge)
    {
        const int eh = t >> 3, gl = t & 7;
        for (int half = 0; half < 2; half++) {
            const int e = half * 32 + eh;
            if (e >= TE) break;
            if (e >= ne) {               // tail: zero-fill so GEMMs stay finite
                bf16x8 zz = {};
                #pragma unroll
                for (int j = 0; j < 6; j++) {
                    int c = gl + j * 8;
                    if (c < 44) *(bf16x8*)&sX[e * SX_STR + c * 8] = zz;
                }
                continue;
            }
            const int ge = e0 + e;
            const int bi = sBi[e], si = sSi[e], ri = sRi[e];
            float v[40];
            #pragma unroll
            for (int j = 0; j < 5; j++) {
                const int c = gl + j * 8;
                const void* base; size_t off;
                if (c < 8)       { base = edges0; off = (size_t)ge * EDIM + c * 8; }
                else if (c < 24) { base = nodes;  off = (size_t)(bi * NNODE + si) * NDIM + (c - 8) * 8; }
                else             { base = nodes;  off = (size_t)(bi * NNODE + ri) * NDIM + (c - 24) * 8; }
                if (isb) {
                    bf16x8 x = *(const bf16x8*)((const bf16*)base + off);
                    #pragma unroll
                    for (int ii = 0; ii < 8; ii++) v[j * 8 + ii] = (float)x[ii];
                } else {
                    const float* sf = (const float*)base + off;
                    float4 f0 = ((const float4*)sf)[0];
                    float4 f1 = ((const float4*)sf)[1];
                    v[j*8+0]=f0.x; v[j*8+1]=f0.y; v[j*8+2]=f0.z; v[j*8+3]=f0.w;
                    v[j*8+4]=f1.x; v[j*8+5]=f1.y; v[j*8+6]=f1.z; v[j*8+7]=f1.w;
                }
            }
            float s = 0.f, sq = 0.f;
            #pragma unroll
            for (int ii = 0; ii < 40; ii++) { s += v[ii]; sq += v[ii] * v[ii]; }
            #pragma unroll
            for (int m = 1; m < 8; m <<= 1) { s += __shfl_xor(s, m); sq += __shfl_xor(sq, m); }
            float mean = s * (1.0f / FIN);
            float var  = sq * (1.0f / FIN) - mean * mean;
            float rstd = rsqrtf(var + 1e-5f);
            #pragma unroll
            for (int j = 0; j < 5; j++) {
                const int c = gl + j * 8;
                const float* gP = &sLnG[c * 8];
                const float* bP = &sLnB[c * 8];
                bf16x8 o;
                #pragma unroll
                for (int ii = 0; ii < 8; ii++)
                    o[ii] = (bf16)((v[j * 8 + ii] - mean) * rstd * gP[ii] + bP[ii]);
                *(bf16x8*)&sX[e * SX_STR + c * 8] = o;
            }
            if (gl < 4) {   // globs chunk c = 40+gl (not LayerNormed)
                const int c = 40 + gl;
                size_t off = (size_t)bi * GDIM + gl * 8;
                bf16x8 o;
                if (isb) {
                    o = *(const bf16x8*)((const bf16*)globs + off);
                } else {
                    const float* sf = (const float*)globs + off;
                    float4 f0 = ((const float4*)sf)[0];
                    float4 f1 = ((const float4*)sf)[1];
                    o[0]=(bf16)f0.x; o[1]=(bf16)f0.y; o[2]=(bf16)f0.z; o[3]=(bf16)f0.w;
                    o[4]=(bf16)f1.x; o[5]=(bf16)f1.y; o[6]=(bf16)f1.z; o[7]=(bf16)f1.w;
                }
                *(bf16x8*)&sX[e * SX_STR + c * 8] = o;
            }
        }
    }
    __syncthreads();

    const int w = t >> 6, lane = t & 63, quad = lane >> 4, l15 = lane & 15;
    f32x4 z = {0.f, 0.f, 0.f, 0.f};

    // Phase 2: GEMM1 X(48x352)@W1T(->256) + X@A1T(->64), B-frags double-buffered
    f32x4 acc[3][4], accA[3];
    #pragma unroll
    for (int s2 = 0; s2 < 3; s2++) { accA[s2] = z; for (int i = 0; i < 4; i++) acc[s2][i] = z; }
    {
        const bf16* pW = W1T + (size_t)(w * 64 + l15) * XD + quad * 8;
        const bf16* pA = A1T + (size_t)(w * 16 + l15) * XD + quad * 8;
        bf16x8 bw[4], ba;
        #pragma unroll
        for (int i = 0; i < 4; i++) bw[i] = *(const bf16x8*)(pW + (size_t)i * 16 * XD);
        ba = *(const bf16x8*)pA;
        #pragma unroll 1
        for (int kk = 0; kk < 11; kk++) {
            bf16x8 bwn[4], ban;
            if (kk < 10) {
                #pragma unroll
                for (int i = 0; i < 4; i++) bwn[i] = *(const bf16x8*)(pW + (size_t)i * 16 * XD + (kk + 1) * 32);
                ban = *(const bf16x8*)(pA + (kk + 1) * 32);
            }
            const int kc = kk * 32 + quad * 8;
            bf16x8 a[3];
            #pragma unroll
            for (int s2 = 0; s2 < 3; s2++) a[s2] = *(bf16x8*)&sX[(s2 * 16 + l15) * SX_STR + kc];
            #pragma unroll
            for (int i = 0; i < 4; i++)
                #pragma unroll
                for (int s2 = 0; s2 < 3; s2++)
                    acc[s2][i] = __builtin_amdgcn_mfma_f32_16x16x32_bf16(a[s2], bw[i], acc[s2][i], 0, 0, 0);
            #pragma unroll
            for (int s2 = 0; s2 < 3; s2++)
                accA[s2] = __builtin_amdgcn_mfma_f32_16x16x32_bf16(a[s2], ba, accA[s2], 0, 0, 0);
            if (kk < 10) {
                #pragma unroll
                for (int i = 0; i < 4; i++) bw[i] = bwn[i];
                ba = ban;
            }
        }
    }
    __syncthreads();   // all sX reads done before overlay writes

    // Phase 3: epilogue -> sH (overlay) and sA (overlay)
    #pragma unroll
    for (int i = 0; i < 4; i++) {
        const int n = w * 64 + i * 16 + l15;
        const float bb = prm[PRM_B1 + n];
        #pragma unroll
        for (int s2 = 0; s2 < 3; s2++)
            #pragma unroll
            for (int r = 0; r < 4; r++)
                sH[(s2 * 16 + quad * 4 + r) * SH_STR + n] = (bf16)siluf(acc[s2][i][r] + bb);
    }
    {
        const int n = w * 16 + l15;
        const float ba1 = prm[PRM_AB1 + n];
        #pragma unroll
        for (int s2 = 0; s2 < 3; s2++)
            #pragma unroll
            for (int r = 0; r < 4; r++)
                sA[(s2 * 16 + quad * 4 + r) * SA_STR + n] = (bf16)siluf(accA[s2][r] + ba1);
    }
    __syncthreads();

    // Phase 4: scores = exp((silu(X@A1)@A2 + ab2)/8) -> plain global stream
    if (t < TE * NHEADS) {
        const int e = t >> 2, h = t & 3;
        if (e < ne) {
            float dot = 0.f;
            #pragma unroll
            for (int c = 0; c < 8; c++) {
                bf16x8 vv = *(bf16x8*)&sA[e * SA_STR + c * 8];
                #pragma unroll
                for (int ii = 0; ii < 8; ii++)
                    dot += (float)vv[ii] * sA2[(c * 8 + ii) * NHEADS + h];
            }
            scrS[(size_t)(e0 + e) * NHEADS + h] = __expf((dot + prm[PRM_AB2 + h]) * 0.125f);
        }
    }

    // Phase 5: GEMM2 H@W2T + b2 + edges0 -> new_edges (no pooled atomics)
    {
        f32x4 c2[3] = {z, z, z};
        const int n = w * 16 + l15;
        const bf16* pW2 = W2T + (size_t)n * H1D + quad * 8;
        bf16x8 b2f = *(const bf16x8*)pW2;
        #pragma unroll 1
        for (int kk = 0; kk < 8; kk++) {
            bf16x8 b2n;
            if (kk < 7) b2n = *(const bf16x8*)(pW2 + (kk + 1) * 32);
            const int kc = kk * 32 + quad * 8;
            #pragma unroll
            for (int s2 = 0; s2 < 3; s2++) {
                bf16x8 a = *(bf16x8*)&sH[(s2 * 16 + l15) * SH_STR + kc];
                c2[s2] = __builtin_amdgcn_mfma_f32_16x16x32_bf16(a, b2f, c2[s2], 0, 0, 0);
            }
            if (kk < 7) b2f = b2n;
        }
        const float bb2 = prm[PRM_B2 + n];
        #pragma unroll
        for (int s2 = 0; s2 < 3; s2++)
            #pragma unroll
            for (int r = 0; r < 4; r++) {
                const int row = s2 * 16 + quad * 4 + r;
                if (row < ne) {
                    size_t off = (size_t)(e0 + row) * EDIM + n;
                    float ev = isb ? (float)((const bf16*)edges0)[off] : ((const float*)edges0)[off];
                    float v = c2[s2][r] + bb2 + ev;
                    if (isb) ((bf16*)outNE)[off] = (bf16)v;
                    else     ((float*)outNE)[off] = v;
                }
            }
    }
}

// ---------------- K_pool: gather-based segment softmax-pool ----------------
__global__ __launch_bounds__(256) void k_pool(const u32* __restrict__ cnt,
                                              const u32* __restrict__ order,
                                              const float* __restrict__ scrS,
                                              const void* __restrict__ nodes,
                                              void* __restrict__ d_out) {
    const int t = threadIdx.x;
    const bool isb = probe_bf16(nodes, t);
    const int ws = blockIdx.x * 4 + (t >> 6);    // segment id, 0..4095
    const int lane = t & 63, h = lane >> 4;
    const void* newE = d_out;                    // edges region of d_out

    const u32 n1 = min(cnt[ws], (u32)CAP);
    const u32 base = (u32)ws * CAP;
    float acc = 0.f, dsum = 0.f;
    u32 i = 0;
    for (; i + 4 <= n1; i += 4) {                // 4-deep to keep loads in flight
        u32 ea = order[base + i], eb = order[base + i + 1];
        u32 ec = order[base + i + 2], ed = order[base + i + 3];
        float sa = scrS[(size_t)ea * NHEADS + h];
        float sb = scrS[(size_t)eb * NHEADS + h];
        float sc = scrS[(size_t)ec * NHEADS + h];
        float sd = scrS[(size_t)ed * NHEADS + h];
        float va = ldf(newE, (size_t)ea * EDIM + lane, isb);
        float vb = ldf(newE, (size_t)eb * EDIM + lane, isb);
        float vc = ldf(newE, (size_t)ec * EDIM + lane, isb);
        float vd = ldf(newE, (size_t)ed * EDIM + lane, isb);
        acc += va * sa + vb * sb + vc * sc + vd * sd;
        dsum += sa + sb + sc + sd;
    }
    for (; i < n1; i++) {
        u32 e = order[base + i];
        float s = scrS[(size_t)e * NHEADS + h];
        acc += ldf(newE, (size_t)e * EDIM + lane, isb) * s;
        dsum += s;
    }
    float r = (dsum > 0.f) ? acc / dsum : 0.f;
    size_t po = (size_t)E_TOT * OUTD + (size_t)ws * OUTD + lane;
    if (isb) ((bf16*)d_out)[po] = (bf16)r;
    else     ((float*)d_out)[po] = r;
}

static char* align_up(char* p, size_t a) {
    return (char*)(((uintptr_t)p + (a - 1)) & ~(uintptr_t)(a - 1));
}

extern "C" void kernel_launch(void* const* d_in, const int* in_sizes, int n_in,
                              void* d_out, int out_size, void* d_ws, size_t ws_size,
                              hipStream_t stream) {
    const void* nodes  = d_in[0];
    const void* edges0 = d_in[1];
    const void* globs  = d_in[2];
    const void* ln_g   = d_in[3];
    const void* ln_b   = d_in[4];
    const void* W1     = d_in[5];
    const void* b1     = d_in[6];
    const void* W2     = d_in[7];
    const void* b2     = d_in[8];
    const void* A1     = d_in[9];
    const void* ab1    = d_in[10];
    const void* A2     = d_in[11];
    const void* ab2    = d_in[12];
    const int*  bidx   = (const int*)d_in[13];
    const int*  sidx   = (const int*)d_in[14];
    const int*  ridx   = (const int*)d_in[15];

    char* p = (char*)d_ws;
    float* prm    = (float*)p;  p = align_up(p + PRM_TOT * 4, 256);
    bf16*  W1T    = (bf16*)p;   p = align_up(p + XD * H1D * 2, 256);
    bf16*  W2T    = (bf16*)p;   p = align_up(p + H1D * OUTD * 2, 256);
    bf16*  A1T    = (bf16*)p;   p = align_up(p + XD * AHD * 2, 256);
    u32*   cnt    = (u32*)p;    p += NSEG * 4;                      // 16 KB
    u32*   order  = (u32*)p;    p += (size_t)NSEG * CAP * 4;        // 3 MB
    float* scrS   = (float*)p;  p += (size_t)E_TOT * NHEADS * 4;    // 4 MB

    hipMemsetAsync(cnt, 0, NSEG * 4, stream);
    k_prep<<<dim3(SOFF + E_TOT / 256), dim3(256), 0, stream>>>(
        nodes, W1, W2, A1, ln_g, ln_b, b1, b2, A2, ab1, ab2,
        bidx, ridx, W1T, W2T, A1T, prm, cnt, order);
    k_edge<<<dim3((E_TOT + TE - 1) / TE), dim3(256), 0, stream>>>(
        nodes, edges0, globs, prm,
        bidx, sidx, ridx, W1T, W2T, A1T, d_out, scrS);
    k_pool<<<dim3(NSEG / 4), dim3(256), 0, stream>>>(cnt, order, scrS, nodes, d_out);
}